// Round 2
// baseline (555.992 us; speedup 1.0000x reference)
//
#include <hip/hip_runtime.h>
#include <hip/hip_bf16.h>

#define N_NODES 50000
#define N_EDGES 800000
#define IN_F 512
#define HID 256
#define HEADS 8
#define DHEAD 32
#define N_CLS 40
#define NCLS_PAD 64

typedef __bf16 bf16x8 __attribute__((ext_vector_type(8)));
typedef float f32x4 __attribute__((ext_vector_type(4)));
typedef float f32x2 __attribute__((ext_vector_type(2)));

// f32 att/bias workspace layout (in floats)
#define AT_AL0 0
#define AT_AR0 256
#define AT_AL1 512
#define AT_AR1 768
#define AT_AL2 1024
#define AT_AR2 1088
#define AT_B0  1152
#define AT_B1  1408
#define AT_B2  1664
#define AT_SZ  1792

__device__ __forceinline__ float ldflag(const void* p, long long i, int isbf) {
  return isbf ? __bfloat162float(((const __hip_bfloat16*)p)[i])
              : ((const float*)p)[i];
}
// unpack a packed bf16 pair (u32): low-address element in low 16 bits
__device__ __forceinline__ float blo(unsigned u) { return __uint_as_float(u << 16); }
__device__ __forceinline__ float bhi(unsigned u) { return __uint_as_float(u & 0xffff0000u); }
// bf16 pair -> f32x2 (feeds v_pk_fma_f32)
__device__ __forceinline__ f32x2 bpair(unsigned u) {
  f32x2 r;
  r.x = __uint_as_float(u << 16);
  r.y = __uint_as_float(u & 0xffff0000u);
  return r;
}
// pack two floats -> bf16 pair in u32
__device__ __forceinline__ unsigned pk2(float a, float b) {
  unsigned x = __bfloat16_as_ushort(__float2bfloat16(a));
  unsigned y = __bfloat16_as_ushort(__float2bfloat16(b));
  return x | (y << 16);
}
// async global->LDS, 16B per lane (LDS dest must be wave-linear: base + lane*16)
__device__ __forceinline__ void gload16(const unsigned short* g, unsigned short* l) {
  __builtin_amdgcn_global_load_lds((__attribute__((address_space(1))) void*)g,
                                   (__attribute__((address_space(3))) void*)l, 16, 0, 0);
}

// ---------------- dtype detect + constant prep + cursor zero (1 block) ----------------
__global__ void k_detect_prep(const unsigned short* __restrict__ raw, int* __restrict__ flag,
                              const void* al0, const void* ar0, const void* al1, const void* ar1,
                              const void* al2, const void* ar2, const void* b0, const void* b1,
                              const void* b2, float* __restrict__ att, int* __restrict__ cursor) {
  __shared__ int cnt[256];
  int t = threadIdx.x;
  for (int i = t; i < N_NODES; i += 256) cursor[i] = 0;   // replaces memset #1
  int c = 0;
  for (int i = t; i < 8192; i += 256) {
    int e = (raw[i] >> 7) & 0xFF;
    if (e >= 0x90) c++;
  }
  cnt[t] = c;
  __syncthreads();
  for (int s = 128; s; s >>= 1) {
    if (t < s) cnt[t] += cnt[t + s];
    __syncthreads();
  }
  __shared__ int sflag;
  if (t == 0) { sflag = (cnt[0] > 64) ? 0 : 1; *flag = sflag; }
  __syncthreads();
  int isbf = sflag;
  att[AT_AL0 + t] = ldflag(al0, t, isbf);
  att[AT_AR0 + t] = ldflag(ar0, t, isbf);
  att[AT_AL1 + t] = ldflag(al1, t, isbf);
  att[AT_AR1 + t] = ldflag(ar1, t, isbf);
  att[AT_B0 + t]  = ldflag(b0, t, isbf);
  att[AT_B1 + t]  = ldflag(b1, t, isbf);
  if (t < N_CLS) {
    att[AT_AL2 + t] = ldflag(al2, t, isbf);
    att[AT_AR2 + t] = ldflag(ar2, t, isbf);
    att[AT_B2 + t]  = ldflag(b2, t, isbf);
  }
}

// ---------------- CSR build (by dst) ----------------
__global__ void k_hist(const int* __restrict__ dst, int* __restrict__ cnt) {
  int e = blockIdx.x * blockDim.x + threadIdx.x;
  if (e < N_EDGES) atomicAdd(&cnt[dst[e]], 1);
}

#define SCAN_B 512
#define SCAN_NB ((N_NODES + SCAN_B - 1) / SCAN_B)   // 98

__global__ __launch_bounds__(SCAN_B) void k_scan_blocks(const int* __restrict__ deg,
                                                        int* __restrict__ excl,
                                                        int* __restrict__ partial) {
  __shared__ int buf[SCAN_B];
  int t = threadIdx.x;
  int i = blockIdx.x * SCAN_B + t;
  int v = (i < N_NODES) ? deg[i] : 0;
  buf[t] = v;
  __syncthreads();
  for (int off = 1; off < SCAN_B; off <<= 1) {
    int x = (t >= off) ? buf[t - off] : 0;
    __syncthreads();
    buf[t] += x;
    __syncthreads();
  }
  if (i < N_NODES) excl[i] = buf[t] - v;
  if (t == SCAN_B - 1) partial[blockIdx.x] = buf[t];
}

__global__ void k_scan_partials(int* __restrict__ partial, int* __restrict__ rowptr) {
  __shared__ int buf[SCAN_NB];
  int t = threadIdx.x;
  if (t < SCAN_NB) buf[t] = partial[t];
  __syncthreads();
  if (t == 0) {
    int run = 0;
    for (int b = 0; b < SCAN_NB; b++) { int v = buf[b]; buf[b] = run; run += v; }
    rowptr[N_NODES] = run;
  }
  __syncthreads();
  if (t < SCAN_NB) partial[t] = buf[t];
}

// adds partial sums AND re-zeros cursor for k_scatter (replaces memset #2)
__global__ void k_scan_add(int* __restrict__ rowptr, const int* __restrict__ partial,
                           int* __restrict__ cursor) {
  int i = blockIdx.x * blockDim.x + threadIdx.x;
  if (i < N_NODES) {
    rowptr[i] += partial[i / SCAN_B];
    cursor[i] = 0;
  }
}

__global__ void k_scatter(const int* __restrict__ src, const int* __restrict__ dst,
                          const int* __restrict__ rowptr, int* __restrict__ cursor,
                          int* __restrict__ csr_src) {
  int e = blockIdx.x * blockDim.x + threadIdx.x;
  if (e < N_EDGES) {
    int d = dst[e];
    int pos = rowptr[d] + atomicAdd(&cursor[d], 1);
    csr_src[pos] = src[e];
  }
}

// ---------------- all 3 weight transposes in one kernel -> bf16 [Ndst][K] ----------------
#define TW0 (HID * IN_F)            // 131072
#define TW1 (TW0 + HID * HID)       // 196608
#define TW2 (TW1 + NCLS_PAD * HID)  // 212992
__global__ void k_transpose_all(const void* __restrict__ W0, const void* __restrict__ W1,
                                const void* __restrict__ W2,
                                __hip_bfloat16* __restrict__ w0t, __hip_bfloat16* __restrict__ w1t,
                                __hip_bfloat16* __restrict__ w2t, const int* __restrict__ flag) {
  int isbf = *flag;
  int i = blockIdx.x * blockDim.x + threadIdx.x;
  if (i < TW0) {                       // w0t[256][512] <- W0[512][256]
    int n = i >> 9, k = i & 511;
    w0t[i] = __float2bfloat16(ldflag(W0, (long long)k * HID + n, isbf));
  } else if (i < TW1) {                // w1t[256][256] <- W1[256][256]
    int j = i - TW0;
    int n = j >> 8, k = j & 255;
    w1t[j] = __float2bfloat16(ldflag(W1, (long long)k * HID + n, isbf));
  } else if (i < TW2) {                // w2t[64][256] <- W2[256][40], pad cols 40..63
    int j = i - TW1;
    int n = j >> 8, k = j & 255;
    float v = (n < N_CLS) ? ldflag(W2, (long long)k * N_CLS + n, isbf) : 0.f;
    w2t[j] = __float2bfloat16(v);
  }
}

// ---------------- A/B staging loads (dual-dtype A: cast fused) ----------------
__device__ __forceinline__ uint4 loadA(const void* A, int isbf, int ga, int M, int K, int off) {
  uint4 av = make_uint4(0u, 0u, 0u, 0u);
  if (ga < M) {
    if (isbf) {
      av = *(const uint4*)((const __hip_bfloat16*)A + (size_t)ga * K + off);
    } else {
      const float* ap = (const float*)A + (size_t)ga * K + off;
      float4 f1 = *(const float4*)ap;
      float4 f2 = *(const float4*)(ap + 4);
      av.x = pk2(f1.x, f1.y); av.y = pk2(f1.z, f1.w);
      av.z = pk2(f2.x, f2.y); av.w = pk2(f2.z, f2.w);
    }
  }
  return av;
}

// ---------------- MFMA bf16 GEMM, 128x128 tile, DOUBLE-BUFFERED prefetch ----------------
// 4 waves, each owns a 64x64 quadrant (4x4 16x16x32 fragments). BK=32.
// T3-minimum 2-phase schedule: per K-step, tile k+1's global_load_lds are issued into
// buf[cur^1] BEFORE the ds_read+MFMA on buf[cur]; the single __syncthreads() (which
// drains vmcnt) sits AFTER the MFMA section, so ~300 cyc of ds_read+MFMA plus 4-5
// co-resident blocks hide the load latency. (Round-1 regression: loads were issued and
// immediately drained with nothing in between -> 16 exposed round-trips, MfmaUtil 5%.)
// Staging: global_load_lds width-16 into LINEAR LDS [128][32] (wave-linear dest as HW
// requires). f32-A fallback: uniform branch, reg-stage + pk2 + ds_write_b128.
// Grid: (M/128)*(N/128), bijective XCD-chunked swizzle, nb-inner so blocks sharing an
// A-panel land on the same XCD's L2.
// fuse_eler: each wave's 64 cols = exactly 2 heads -> el/er in-epilogue.
__global__ __launch_bounds__(256) void k_gemm128(const void* __restrict__ A,
                                                 const __hip_bfloat16* __restrict__ Bt,
                                                 __hip_bfloat16* __restrict__ C,
                                                 int M, int K, int N,
                                                 const int* __restrict__ flag, int force_bf,
                                                 const float* __restrict__ al,
                                                 const float* __restrict__ ar,
                                                 float* __restrict__ el,
                                                 float* __restrict__ er, int fuse_eler) {
  __shared__ unsigned short sA[2][128 * 32];   // 2 x 8 KB, linear [row][32]
  __shared__ unsigned short sB[2][128 * 32];
  const int isbf = force_bf ? 1 : *flag;
  // bijective XCD-chunked swizzle (m204): logical id = mb*nblk + nb
  int nwg = gridDim.x;
  int q = nwg >> 3, r = nwg & 7;
  int xcd = blockIdx.x & 7, lid = blockIdx.x >> 3;
  int logical = (xcd < r ? xcd * (q + 1) : r * (q + 1) + (xcd - r) * q) + lid;
  int nblk = N >> 7;
  int mb = logical / nblk;
  int nb = logical - mb * nblk;
  int m0 = mb * 128, n0 = nb * 128;
  int tid = threadIdx.x;
  int wave = tid >> 6, lane = tid & 63;
  int wm = (wave >> 1) * 64, wn = (wave & 1) * 64;
  int lm = lane & 15, quad = lane >> 4;
  // staging chunk ids: each wave covers 128 contiguous 16B chunks (2 issues x 64 lanes)
  int c0 = (wave << 7) + lane, c1 = c0 + 64;
  int rA0 = c0 >> 2, rA1 = c1 >> 2;             // tile row of each chunk
  int col0 = (c0 & 3) << 3, col1 = (c1 & 3) << 3;  // element offset within row
  int gr0 = m0 + rA0; if (gr0 > M - 1) gr0 = M - 1;  // clamp tail rows (no OOB)
  int gr1 = m0 + rA1; if (gr1 > M - 1) gr1 = M - 1;
  const unsigned short* Ab = (const unsigned short*)A;
  const float* Af = (const float*)A;
  const unsigned short* Bb = (const unsigned short*)Bt;
  size_t aog0 = (size_t)gr0 * K + col0;
  size_t aog1 = (size_t)gr1 * K + col1;
  size_t bog0 = (size_t)(n0 + rA0) * K + col0;
  size_t bog1 = (size_t)(n0 + rA1) * K + col1;
  int lo0 = c0 << 3, lo1 = c1 << 3;             // LDS element offsets of the two chunks
  // fragment LDS byte offsets within a buffer (row pitch 64B)
  int fq = quad << 4;
  int aoff[4], boff[4];
  #pragma unroll
  for (int i = 0; i < 4; i++) {
    aoff[i] = ((wm + i * 16 + lm) << 6) + fq;
    boff[i] = ((wn + i * 16 + lm) << 6) + fq;
  }
  f32x4 acc[4][4] = {};
  // ---- prologue: stage tile 0 into buffer 0 ----
  if (isbf) {
    gload16(Ab + aog0, &sA[0][lo0]);
    gload16(Ab + aog1, &sA[0][lo1]);
  } else {
    const float* p0 = Af + aog0;
    const float* p1 = Af + aog1;
    float4 x0 = *(const float4*)p0, y0 = *(const float4*)(p0 + 4);
    float4 x1 = *(const float4*)p1, y1 = *(const float4*)(p1 + 4);
    *(uint4*)&sA[0][lo0] = make_uint4(pk2(x0.x, x0.y), pk2(x0.z, x0.w), pk2(y0.x, y0.y), pk2(y0.z, y0.w));
    *(uint4*)&sA[0][lo1] = make_uint4(pk2(x1.x, x1.y), pk2(x1.z, x1.w), pk2(y1.x, y1.y), pk2(y1.z, y1.w));
  }
  gload16(Bb + bog0, &sB[0][lo0]);
  gload16(Bb + bog1, &sB[0][lo1]);
  __syncthreads();                         // drain prologue staging (vmcnt+lgkm)
  int cur = 0;
  for (int k0 = 0; k0 < K; k0 += 32) {
    int nxt = cur ^ 1;
    // issue tile k+1's staging FIRST; it drains at this iteration's closing barrier
    if (k0 + 32 < K) {
      if (isbf) {
        gload16(Ab + aog0 + k0 + 32, &sA[nxt][lo0]);
        gload16(Ab + aog1 + k0 + 32, &sA[nxt][lo1]);
      } else {
        const float* p0 = Af + aog0 + k0 + 32;
        const float* p1 = Af + aog1 + k0 + 32;
        float4 x0 = *(const float4*)p0, y0 = *(const float4*)(p0 + 4);
        float4 x1 = *(const float4*)p1, y1 = *(const float4*)(p1 + 4);
        *(uint4*)&sA[nxt][lo0] = make_uint4(pk2(x0.x, x0.y), pk2(x0.z, x0.w), pk2(y0.x, y0.y), pk2(y0.z, y0.w));
        *(uint4*)&sA[nxt][lo1] = make_uint4(pk2(x1.x, x1.y), pk2(x1.z, x1.w), pk2(y1.x, y1.y), pk2(y1.z, y1.w));
      }
      gload16(Bb + bog0 + k0 + 32, &sB[nxt][lo0]);
      gload16(Bb + bog1 + k0 + 32, &sB[nxt][lo1]);
    }
    const char* sAb = (const char*)&sA[cur][0];
    const char* sBb = (const char*)&sB[cur][0];
    bf16x8 af[4], bfr[4];
    #pragma unroll
    for (int i = 0; i < 4; i++) {
      af[i]  = *(const bf16x8*)(sAb + aoff[i]);
      bfr[i] = *(const bf16x8*)(sBb + boff[i]);
    }
    #pragma unroll
    for (int mi = 0; mi < 4; mi++)
      #pragma unroll
      for (int ni = 0; ni < 4; ni++)
        acc[mi][ni] = __builtin_amdgcn_mfma_f32_16x16x32_bf16(af[mi], bfr[ni], acc[mi][ni], 0, 0, 0);
    __syncthreads();                     // next tile staged + all reads of cur done
    cur = nxt;
  }
  // C/D layout: col = lane&15, row = quad*4 + r (m89/m91 verified)
  #pragma unroll
  for (int mi = 0; mi < 4; mi++) {
    #pragma unroll
    for (int r2 = 0; r2 < 4; r2++) {
      int gm = m0 + wm + mi * 16 + (quad << 2) + r2;
      if (gm < M) {
        #pragma unroll
        for (int ni = 0; ni < 4; ni++) {
          int gn = n0 + wn + ni * 16 + lm;
          C[(size_t)gm * N + gn] = __float2bfloat16(acc[mi][ni][r2]);
        }
      }
    }
  }
  if (fuse_eler) {
    // this wave's cols n0+wn .. n0+wn+63 = heads h0, h0+1
    int h0 = (n0 + wn) >> 5;
    float ala[4], ara[4];
    #pragma unroll
    for (int ni = 0; ni < 4; ni++) {
      int idx = (h0 + (ni >> 1)) * DHEAD + ((ni & 1) << 4) + lm;
      ala[ni] = al[idx];
      ara[ni] = ar[idx];
    }
    #pragma unroll
    for (int mi = 0; mi < 4; mi++)
      #pragma unroll
      for (int r2 = 0; r2 < 4; r2++) {
        int gm = m0 + wm + mi * 16 + (quad << 2) + r2;
        #pragma unroll
        for (int hp = 0; hp < 2; hp++) {
          float pl = acc[mi][2 * hp][r2] * ala[2 * hp] + acc[mi][2 * hp + 1][r2] * ala[2 * hp + 1];
          float pr = acc[mi][2 * hp][r2] * ara[2 * hp] + acc[mi][2 * hp + 1][r2] * ara[2 * hp + 1];
          #pragma unroll
          for (int d = 1; d < 16; d <<= 1) {   // butterfly over the 16 lm lanes (same quad)
            pl += __shfl_xor(pl, d, 16);
            pr += __shfl_xor(pr, d, 16);
          }
          if (lm == 0 && gm < M) {
            el[gm * HEADS + h0 + hp] = pl;
            er[gm * HEADS + h0 + hp] = pr;
          }
        }
      }
  }
}

// ---------------- MFMA bf16 GEMM, 64x64 tile (kept for layer 2, N=64) ----------------
__global__ __launch_bounds__(256) void k_gemm64(const void* __restrict__ A,
                                                const __hip_bfloat16* __restrict__ Bt,
                                                __hip_bfloat16* __restrict__ C,
                                                int M, int K, int N,
                                                const int* __restrict__ flag, int force_bf,
                                                const float* __restrict__ al,
                                                const float* __restrict__ ar,
                                                float* __restrict__ el,
                                                float* __restrict__ er, int fuse_eler) {
  __shared__ unsigned short As[64][40];  // 80 B pitch: 16B-aligned rows, spreads banks
  __shared__ unsigned short Bs[64][40];
  const int isbf = force_bf ? 1 : *flag;
  int nblk = N >> 6;
  int per = nblk << 3;                 // blocks per group
  int g = blockIdx.x / per;
  int i2 = blockIdx.x - g * per;
  int mb = g * 8 + (i2 & 7);
  int nb = i2 >> 3;
  int m0 = mb * 64, n0 = nb * 64;
  if (m0 >= M) return;
  int tid = threadIdx.x;
  int lrow = tid >> 2;          // 0..63
  int lcol = (tid & 3) * 8;     // 0,8,16,24
  int wave = tid >> 6, lane = tid & 63;
  int wm = (wave >> 1) * 32, wn = (wave & 1) * 32;
  int lm = lane & 15, quad = lane >> 4;
  f32x4 acc[2][2] = {};
  // prologue load for k0 = 0
  uint4 av = loadA(A, isbf, m0 + lrow, M, K, lcol);
  uint4 bv = *(const uint4*)(Bt + (size_t)(n0 + lrow) * K + lcol);
  for (int k0 = 0; k0 < K; k0 += 32) {
    __syncthreads();            // previous iteration's LDS reads done
    *(uint4*)(&As[lrow][lcol]) = av;
    *(uint4*)(&Bs[lrow][lcol]) = bv;
    __syncthreads();
    // issue k+1's loads now; they drain behind the MFMA section below
    uint4 avn = make_uint4(0u, 0u, 0u, 0u), bvn = make_uint4(0u, 0u, 0u, 0u);
    if (k0 + 32 < K) {
      avn = loadA(A, isbf, m0 + lrow, M, K, k0 + 32 + lcol);
      bvn = *(const uint4*)(Bt + (size_t)(n0 + lrow) * K + k0 + 32 + lcol);
    }
    bf16x8 af[2], bfr[2];
    #pragma unroll
    for (int i = 0; i < 2; i++) {
      af[i]  = *(const bf16x8*)(&As[wm + i * 16 + lm][quad * 8]);
      bfr[i] = *(const bf16x8*)(&Bs[wn + i * 16 + lm][quad * 8]);
    }
    #pragma unroll
    for (int mi = 0; mi < 2; mi++)
      #pragma unroll
      for (int ni = 0; ni < 2; ni++)
        acc[mi][ni] = __builtin_amdgcn_mfma_f32_16x16x32_bf16(af[mi], bfr[ni], acc[mi][ni], 0, 0, 0);
    av = avn; bv = bvn;
  }
  // C/D layout: col = lane&15, row = quad*4 + r  (m89/m91 verified)
  #pragma unroll
  for (int mi = 0; mi < 2; mi++)
    #pragma unroll
    for (int ni = 0; ni < 2; ni++)
      #pragma unroll
      for (int r = 0; r < 4; r++) {
        int gm = m0 + wm + mi * 16 + quad * 4 + r;
        int gn = n0 + wn + ni * 16 + lm;
        if (gm < M) C[(size_t)gm * N + gn] = __float2bfloat16(acc[mi][ni][r]);
      }
  if (fuse_eler) {
    int hg = (n0 + wn) >> 5;
    float ala[2], ara[2];
    #pragma unroll
    for (int ni = 0; ni < 2; ni++) {
      ala[ni] = al[hg * DHEAD + ni * 16 + lm];
      ara[ni] = ar[hg * DHEAD + ni * 16 + lm];
    }
    #pragma unroll
    for (int mi = 0; mi < 2; mi++)
      #pragma unroll
      for (int r = 0; r < 4; r++) {
        float pl = acc[mi][0][r] * ala[0] + acc[mi][1][r] * ala[1];
        float pr = acc[mi][0][r] * ara[0] + acc[mi][1][r] * ara[1];
        #pragma unroll
        for (int d = 1; d < 16; d <<= 1) {
          pl += __shfl_xor(pl, d, 16);
          pr += __shfl_xor(pr, d, 16);
        }
        int gm = m0 + wm + mi * 16 + quad * 4 + r;
        if (lm == 0 && gm < M) {
          el[gm * HEADS + hg] = pl;
          er[gm * HEADS + hg] = pr;
        }
      }
  }
}

// ---------------- el/er for layer 2 (1 head, 40 dims, stride 64) ----------------
__global__ void k_eler2(const __hip_bfloat16* __restrict__ feat2,
                        const float* __restrict__ al, const float* __restrict__ ar,
                        float* __restrict__ el, float* __restrict__ er) {
  int n = blockIdx.x * blockDim.x + threadIdx.x;
  if (n >= N_NODES) return;
  const __hip_bfloat16* f = feat2 + (size_t)n * NCLS_PAD;
  float sl = 0.f, sr = 0.f;
  for (int d = 0; d < N_CLS; d++) {
    float v = __bfloat162float(f[d]);
    sl += v * al[d];
    sr += v * ar[d];
  }
  el[n] = sl;
  er[n] = sr;
}

// ---------------- fused edge-softmax + aggregation, 8 slots x 32 lanes ----------------
// lane owns 8 channels (uint4/edge). No max-subtraction (shift-invariant, exp clamped).
// Unroll-2: two independent csr->el/feat gather chains in flight.
// f32x2 accumulators -> v_pk_fma_f32; 32-bit byte offsets -> saddr+voffset loads.
__global__ __launch_bounds__(256) void k_aggregate8(const int* __restrict__ rowptr,
                                                    const int* __restrict__ csr_src,
                                                    const uint4* __restrict__ feat_rows,
                                                    const float* __restrict__ el,
                                                    const float* __restrict__ er,
                                                    const float* __restrict__ bias,
                                                    __hip_bfloat16* __restrict__ out) {
  __shared__ float lds_acc[8][256];
  __shared__ float lds_l[8][32];
  int n = blockIdx.x;
  int t = threadIdx.x;
  int slot = t >> 5;      // 0..7
  int c = t & 31;         // channel group: channels c*8..c*8+7
  int hh = c >> 2;        // head of this group
  float er_n = er[n * HEADS + hh];
  int beg = rowptr[n], end = rowptr[n + 1];
  float l = 0.f;
  f32x2 a0 = {0.f, 0.f}, a1 = {0.f, 0.f}, a2 = {0.f, 0.f}, a3 = {0.f, 0.f};
  const char* fb = (const char*)feat_rows;
  unsigned cb = (unsigned)c << 4;
  int i = beg + slot;
  for (; i + 8 < end; i += 16) {
    int s1 = csr_src[i];
    int s2 = csr_src[i + 8];
    float el1 = el[s1 * HEADS + hh];
    float el2 = el[s2 * HEADS + hh];
    uint4 f1 = *(const uint4*)(fb + (((unsigned)s1 << 9) | cb));
    uint4 f2 = *(const uint4*)(fb + (((unsigned)s2 << 9) | cb));
    float x1 = el1 + er_n, x2 = el2 + er_n;
    float e1 = x1 > 0.f ? x1 : 0.2f * x1;
    float e2 = x2 > 0.f ? x2 : 0.2f * x2;
    float p1 = __expf(fminf(e1, 60.f));
    float p2 = __expf(fminf(e2, 60.f));
    l += p1 + p2;
    a0 += bpair(f1.x) * p1; a1 += bpair(f1.y) * p1;
    a2 += bpair(f1.z) * p1; a3 += bpair(f1.w) * p1;
    a0 += bpair(f2.x) * p2; a1 += bpair(f2.y) * p2;
    a2 += bpair(f2.z) * p2; a3 += bpair(f2.w) * p2;
  }
  if (i < end) {
    int s = csr_src[i];
    float elv = el[s * HEADS + hh];
    uint4 fv = *(const uint4*)(fb + (((unsigned)s << 9) | cb));
    float x = elv + er_n;
    float e = x > 0.f ? x : 0.2f * x;
    float p = __expf(fminf(e, 60.f));
    l += p;
    a0 += bpair(fv.x) * p; a1 += bpair(fv.y) * p;
    a2 += bpair(fv.z) * p; a3 += bpair(fv.w) * p;
  }
  *(float4*)&lds_acc[slot][c * 8]     = make_float4(a0.x, a0.y, a1.x, a1.y);
  *(float4*)&lds_acc[slot][c * 8 + 4] = make_float4(a2.x, a2.y, a3.x, a3.y);
  lds_l[slot][c] = l;
  __syncthreads();
  float a = 0.f, L = 0.f;
  #pragma unroll
  for (int s2 = 0; s2 < 8; s2++) { a += lds_acc[s2][t]; L += lds_l[s2][t >> 3]; }
  float o = a / fmaxf(L, 1e-9f) + bias[t];
  o = fmaxf(o, 0.f);                            // ReLU (layers 0,1)
  out[(size_t)n * HID + t] = __float2bfloat16(o);
}

// ---------------- layer 2 aggregate: 32 slots x 8 lanes (64-ch padded rows) ----------------
__global__ __launch_bounds__(256) void k_aggregate1(const int* __restrict__ rowptr,
                                                    const int* __restrict__ csr_src,
                                                    const uint4* __restrict__ fr2,  // [N][8] uint4
                                                    const float* __restrict__ el,
                                                    const float* __restrict__ er,
                                                    const float* __restrict__ bias,
                                                    void* __restrict__ out,
                                                    const int* __restrict__ flag) {
  __shared__ float lds_acc[32][64];
  __shared__ float lds_l[32][8];
  int isbf = *flag;
  int n = blockIdx.x;
  int t = threadIdx.x;
  int slot = t >> 3;      // 0..31
  int c = t & 7;
  float er_n = er[n];
  int beg = rowptr[n], end = rowptr[n + 1];
  float l = 0.f;
  f32x2 a0 = {0.f, 0.f}, a1 = {0.f, 0.f}, a2 = {0.f, 0.f}, a3 = {0.f, 0.f};
  const char* fb = (const char*)fr2;
  unsigned cb = (unsigned)c << 4;
  int i = beg + slot;
  for (; i + 32 < end; i += 64) {
    int s1 = csr_src[i], s2 = csr_src[i + 32];
    float el1 = el[s1], el2 = el[s2];
    uint4 f1 = *(const uint4*)(fb + (((unsigned)s1 << 7) | cb));
    uint4 f2 = *(const uint4*)(fb + (((unsigned)s2 << 7) | cb));
    float x1 = el1 + er_n, x2 = el2 + er_n;
    float e1 = x1 > 0.f ? x1 : 0.2f * x1;
    float e2 = x2 > 0.f ? x2 : 0.2f * x2;
    float p1 = __expf(fminf(e1, 60.f));
    float p2 = __expf(fminf(e2, 60.f));
    l += p1 + p2;
    a0 += bpair(f1.x) * p1; a1 += bpair(f1.y) * p1;
    a2 += bpair(f1.z) * p1; a3 += bpair(f1.w) * p1;
    a0 += bpair(f2.x) * p2; a1 += bpair(f2.y) * p2;
    a2 += bpair(f2.z) * p2; a3 += bpair(f2.w) * p2;
  }
  if (i < end) {
    int s = csr_src[i];
    float x = el[s] + er_n;
    uint4 fv = *(const uint4*)(fb + (((unsigned)s << 7) | cb));
    float e = x > 0.f ? x : 0.2f * x;
    float p = __expf(fminf(e, 60.f));
    l += p;
    a0 += bpair(fv.x) * p; a1 += bpair(fv.y) * p;
    a2 += bpair(fv.z) * p; a3 += bpair(fv.w) * p;
  }
  *(float4*)&lds_acc[slot][c * 8]     = make_float4(a0.x, a0.y, a1.x, a1.y);
  *(float4*)&lds_acc[slot][c * 8 + 4] = make_float4(a2.x, a2.y, a3.x, a3.y);
  lds_l[slot][c] = l;
  __syncthreads();
  if (t < N_CLS) {
    float a = 0.f, L = 0.f;
    #pragma unroll
    for (int s2 = 0; s2 < 32; s2++) { a += lds_acc[s2][t]; L += lds_l[s2][t >> 3]; }
    float o = a / fmaxf(L, 1e-9f) + bias[t];    // no ReLU on output layer
    if (isbf) ((__hip_bfloat16*)out)[(size_t)n * N_CLS + t] = __float2bfloat16(o);
    else      ((float*)out)[(size_t)n * N_CLS + t] = o;
  }
}

// ---------------- launch ----------------
static inline size_t align_up(size_t x) { return (x + 255) & ~(size_t)255; }

extern "C" void kernel_launch(void* const* d_in, const int* in_sizes, int n_in,
                              void* d_out, int out_size, void* d_ws, size_t ws_size,
                              hipStream_t stream) {
  const void* in_feat = d_in[0];
  const int* src = (const int*)d_in[1];
  const int* dst = (const int*)d_in[2];
  const void* W0  = d_in[3];
  const void* al0 = d_in[4];
  const void* ar0 = d_in[5];
  const void* b0  = d_in[6];
  const void* W1  = d_in[7];
  const void* al1 = d_in[8];
  const void* ar1 = d_in[9];
  const void* b1  = d_in[10];
  const void* W2  = d_in[11];
  const void* al2 = d_in[12];
  const void* ar2 = d_in[13];
  const void* b2  = d_in[14];

  char* p = (char*)d_ws;
  int* flag = (int*)p;                   p += 256;
  float* att = (float*)p;                p += align_up(AT_SZ * sizeof(float));
  int* rowptr = (int*)p;                 p += align_up((N_NODES + 1) * sizeof(int));
  int* cursor = (int*)p;                 p += align_up(N_NODES * sizeof(int));
  int* csr_src = (int*)p;                p += align_up(N_EDGES * sizeof(int));
  int* partial = (int*)p;                p += align_up(SCAN_NB * sizeof(int));
  __hip_bfloat16* feat16 = (__hip_bfloat16*)p; p += align_up((size_t)N_NODES * HID * sizeof(__hip_bfloat16));
  __hip_bfloat16* h16 = (__hip_bfloat16*)p;    p += align_up((size_t)N_NODES * HID * sizeof(__hip_bfloat16));
  float* el = (float*)p;                 p += align_up((size_t)N_NODES * HEADS * sizeof(float));
  float* er = (float*)p;                 p += align_up((size_t)N_NODES * HEADS * sizeof(float));
  __hip_bfloat16* w0t = (__hip_bfloat16*)p;    p += align_up((size_t)HID * IN_F * sizeof(__hip_bfloat16));
  __hip_bfloat16* w1t = (__hip_bfloat16*)p;    p += align_up((size_t)HID * HID * sizeof(__hip_bfloat16));
  __hip_bfloat16* w2t = (__hip_bfloat16*)p;    p += align_up((size_t)NCLS_PAD * HID * sizeof(__hip_bfloat16));

  const int EB = (N_EDGES + 255) / 256;
  const int MB64 = (N_NODES + 63) / 64;          // 782
  const int GROUPS = (MB64 + 7) / 8;             // 98
  const int G1 = GROUPS * 8 * 1;                 // layer-2 swizzled grid (784)
  const int MB128 = (N_NODES + 127) / 128;       // 391
  const int GX = MB128 * 2;                      // 128x128 tiles, N=256 (782)

  // ---- dtype detection + constant prep + cursor zero ----
  k_detect_prep<<<1, 256, 0, stream>>>((const unsigned short*)in_feat, flag,
                                       al0, ar0, al1, ar1, al2, ar2, b0, b1, b2, att, cursor);

  // ---- CSR build ----
  k_hist<<<EB, 256, 0, stream>>>(dst, cursor);
  k_scan_blocks<<<SCAN_NB, SCAN_B, 0, stream>>>(cursor, rowptr, partial);
  k_scan_partials<<<1, 128, 0, stream>>>(partial, rowptr);
  k_scan_add<<<(N_NODES + 255) / 256, 256, 0, stream>>>(rowptr, partial, cursor);
  k_scatter<<<EB, 256, 0, stream>>>(src, dst, rowptr, cursor, csr_src);

  // ---- weight transposes (merged, -> bf16 [N][K]) ----
  k_transpose_all<<<(TW2 + 255) / 256, 256, 0, stream>>>(W0, W1, W2, w0t, w1t, w2t, flag);

  // ---- layer 0 (cast + el/er fused into GEMM) ----
  k_gemm128<<<GX, 256, 0, stream>>>(in_feat, w0t, feat16, N_NODES, IN_F, HID, flag, 0,
                                    att + AT_AL0, att + AT_AR0, el, er, 1);
  k_aggregate8<<<N_NODES, 256, 0, stream>>>(rowptr, csr_src, (const uint4*)feat16, el, er, att + AT_B0, h16);

  // ---- layer 1 ----
  k_gemm128<<<GX, 256, 0, stream>>>(h16, w1t, feat16, N_NODES, HID, HID, flag, 1,
                                    att + AT_AL1, att + AT_AR1, el, er, 1);
  k_aggregate8<<<N_NODES, 256, 0, stream>>>(rowptr, csr_src, (const uint4*)feat16, el, er, att + AT_B1, h16);

  // ---- layer 2 (feat16 reused as [N][64] padded feat2) ----
  k_gemm64<<<G1, 256, 0, stream>>>(h16, w2t, feat16, N_NODES, HID, NCLS_PAD, flag, 1,
                                   nullptr, nullptr, nullptr, nullptr, 0);
  k_eler2<<<(N_NODES + 255) / 256, 256, 0, stream>>>(feat16, att + AT_AL2, att + AT_AR2, el, er);
  k_aggregate1<<<N_NODES, 256, 0, stream>>>(rowptr, csr_src, (const uint4*)feat16, el, er, att + AT_B2, d_out, flag);
}

// Round 4
// 550.023 us; speedup vs baseline: 1.0109x; 1.0109x over previous
//
#include <hip/hip_runtime.h>
#include <hip/hip_bf16.h>

#define N_NODES 50000
#define N_EDGES 800000
#define IN_F 512
#define HID 256
#define HEADS 8
#define DHEAD 32
#define N_CLS 40
#define NCLS_PAD 64

typedef __bf16 bf16x8 __attribute__((ext_vector_type(8)));
typedef float f32x4 __attribute__((ext_vector_type(4)));
typedef float f32x2 __attribute__((ext_vector_type(2)));

// f32 att/bias workspace layout (in floats)
#define AT_AL0 0
#define AT_AR0 256
#define AT_AL1 512
#define AT_AR1 768
#define AT_AL2 1024
#define AT_AR2 1088
#define AT_B0  1152
#define AT_B1  1408
#define AT_B2  1664
#define AT_SZ  1792

__device__ __forceinline__ float ldflag(const void* p, long long i, int isbf) {
  return isbf ? __bfloat162float(((const __hip_bfloat16*)p)[i])
              : ((const float*)p)[i];
}
// unpack a packed bf16 pair (u32): low-address element in low 16 bits
__device__ __forceinline__ float blo(unsigned u) { return __uint_as_float(u << 16); }
__device__ __forceinline__ float bhi(unsigned u) { return __uint_as_float(u & 0xffff0000u); }
// bf16 pair -> f32x2 (feeds v_pk_fma_f32)
__device__ __forceinline__ f32x2 bpair(unsigned u) {
  f32x2 r;
  r.x = __uint_as_float(u << 16);
  r.y = __uint_as_float(u & 0xffff0000u);
  return r;
}
// pack two floats -> bf16 pair in u32
__device__ __forceinline__ unsigned pk2(float a, float b) {
  unsigned x = __bfloat16_as_ushort(__float2bfloat16(a));
  unsigned y = __bfloat16_as_ushort(__float2bfloat16(b));
  return x | (y << 16);
}
// async global->LDS, 16B per lane (LDS dest must be wave-linear: base + lane*16)
__device__ __forceinline__ void gload16(const unsigned short* g, unsigned short* l) {
  __builtin_amdgcn_global_load_lds((__attribute__((address_space(1))) void*)g,
                                   (__attribute__((address_space(3))) void*)l, 16, 0, 0);
}

// ---------------- dtype detect + constant prep + cursor zero (1 block) ----------------
__global__ void k_detect_prep(const unsigned short* __restrict__ raw, int* __restrict__ flag,
                              const void* al0, const void* ar0, const void* al1, const void* ar1,
                              const void* al2, const void* ar2, const void* b0, const void* b1,
                              const void* b2, float* __restrict__ att, int* __restrict__ cursor) {
  __shared__ int cnt[256];
  int t = threadIdx.x;
  for (int i = t; i < N_NODES; i += 256) cursor[i] = 0;   // replaces memset #1
  int c = 0;
  for (int i = t; i < 8192; i += 256) {
    int e = (raw[i] >> 7) & 0xFF;
    if (e >= 0x90) c++;
  }
  cnt[t] = c;
  __syncthreads();
  for (int s = 128; s; s >>= 1) {
    if (t < s) cnt[t] += cnt[t + s];
    __syncthreads();
  }
  __shared__ int sflag;
  if (t == 0) { sflag = (cnt[0] > 64) ? 0 : 1; *flag = sflag; }
  __syncthreads();
  int isbf = sflag;
  att[AT_AL0 + t] = ldflag(al0, t, isbf);
  att[AT_AR0 + t] = ldflag(ar0, t, isbf);
  att[AT_AL1 + t] = ldflag(al1, t, isbf);
  att[AT_AR1 + t] = ldflag(ar1, t, isbf);
  att[AT_B0 + t]  = ldflag(b0, t, isbf);
  att[AT_B1 + t]  = ldflag(b1, t, isbf);
  if (t < N_CLS) {
    att[AT_AL2 + t] = ldflag(al2, t, isbf);
    att[AT_AR2 + t] = ldflag(ar2, t, isbf);
    att[AT_B2 + t]  = ldflag(b2, t, isbf);
  }
}

// ---------------- CSR build (by dst) ----------------
__global__ void k_hist(const int* __restrict__ dst, int* __restrict__ cnt) {
  int e = blockIdx.x * blockDim.x + threadIdx.x;
  if (e < N_EDGES) atomicAdd(&cnt[dst[e]], 1);
}

#define SCAN_B 512
#define SCAN_NB ((N_NODES + SCAN_B - 1) / SCAN_B)   // 98

__global__ __launch_bounds__(SCAN_B) void k_scan_blocks(const int* __restrict__ deg,
                                                        int* __restrict__ excl,
                                                        int* __restrict__ partial) {
  __shared__ int buf[SCAN_B];
  int t = threadIdx.x;
  int i = blockIdx.x * SCAN_B + t;
  int v = (i < N_NODES) ? deg[i] : 0;
  buf[t] = v;
  __syncthreads();
  for (int off = 1; off < SCAN_B; off <<= 1) {
    int x = (t >= off) ? buf[t - off] : 0;
    __syncthreads();
    buf[t] += x;
    __syncthreads();
  }
  if (i < N_NODES) excl[i] = buf[t] - v;
  if (t == SCAN_B - 1) partial[blockIdx.x] = buf[t];
}

__global__ void k_scan_partials(int* __restrict__ partial, int* __restrict__ rowptr) {
  __shared__ int buf[SCAN_NB];
  int t = threadIdx.x;
  if (t < SCAN_NB) buf[t] = partial[t];
  __syncthreads();
  if (t == 0) {
    int run = 0;
    for (int b = 0; b < SCAN_NB; b++) { int v = buf[b]; buf[b] = run; run += v; }
    rowptr[N_NODES] = run;
  }
  __syncthreads();
  if (t < SCAN_NB) partial[t] = buf[t];
}

// adds partial sums AND re-zeros cursor for k_scatter (replaces memset #2)
__global__ void k_scan_add(int* __restrict__ rowptr, const int* __restrict__ partial,
                           int* __restrict__ cursor) {
  int i = blockIdx.x * blockDim.x + threadIdx.x;
  if (i < N_NODES) {
    rowptr[i] += partial[i / SCAN_B];
    cursor[i] = 0;
  }
}

__global__ void k_scatter(const int* __restrict__ src, const int* __restrict__ dst,
                          const int* __restrict__ rowptr, int* __restrict__ cursor,
                          int* __restrict__ csr_src) {
  int e = blockIdx.x * blockDim.x + threadIdx.x;
  if (e < N_EDGES) {
    int d = dst[e];
    int pos = rowptr[d] + atomicAdd(&cursor[d], 1);
    csr_src[pos] = src[e];
  }
}

// ---------------- all 3 weight transposes in one kernel -> bf16 [Ndst][K] ----------------
#define TW0 (HID * IN_F)            // 131072
#define TW1 (TW0 + HID * HID)       // 196608
#define TW2 (TW1 + NCLS_PAD * HID)  // 212992
__global__ void k_transpose_all(const void* __restrict__ W0, const void* __restrict__ W1,
                                const void* __restrict__ W2,
                                __hip_bfloat16* __restrict__ w0t, __hip_bfloat16* __restrict__ w1t,
                                __hip_bfloat16* __restrict__ w2t, const int* __restrict__ flag) {
  int isbf = *flag;
  int i = blockIdx.x * blockDim.x + threadIdx.x;
  if (i < TW0) {                       // w0t[256][512] <- W0[512][256]
    int n = i >> 9, k = i & 511;
    w0t[i] = __float2bfloat16(ldflag(W0, (long long)k * HID + n, isbf));
  } else if (i < TW1) {                // w1t[256][256] <- W1[256][256]
    int j = i - TW0;
    int n = j >> 8, k = j & 255;
    w1t[j] = __float2bfloat16(ldflag(W1, (long long)k * HID + n, isbf));
  } else if (i < TW2) {                // w2t[64][256] <- W2[256][40], pad cols 40..63
    int j = i - TW1;
    int n = j >> 8, k = j & 255;
    float v = (n < N_CLS) ? ldflag(W2, (long long)k * N_CLS + n, isbf) : 0.f;
    w2t[j] = __float2bfloat16(v);
  }
}

// ---------------- A/B staging loads (dual-dtype A: cast fused) ----------------
__device__ __forceinline__ uint4 loadA(const void* A, int isbf, int ga, int M, int K, int off) {
  uint4 av = make_uint4(0u, 0u, 0u, 0u);
  if (ga < M) {
    if (isbf) {
      av = *(const uint4*)((const __hip_bfloat16*)A + (size_t)ga * K + off);
    } else {
      const float* ap = (const float*)A + (size_t)ga * K + off;
      float4 f1 = *(const float4*)ap;
      float4 f2 = *(const float4*)(ap + 4);
      av.x = pk2(f1.x, f1.y); av.y = pk2(f1.z, f1.w);
      av.z = pk2(f2.x, f2.y); av.w = pk2(f2.z, f2.w);
    }
  }
  return av;
}

// ---------------- MFMA bf16 GEMM, 128x128 tile, distance-2 counted-vmcnt pipeline ----------------
// 4 waves, each owns a 64x64 quadrant (4x4 16x16x32 fragments). BK=32. TRIPLE-buffered LDS.
// T4 schedule (rounds 1-2 post-mortem: __syncthreads drains vmcnt(0) -> every K-step exposed
// a full cold-HBM round trip; MfmaUtil ~6%). Per K-step:
//   s_waitcnt vmcnt(4)   <- only tile t's 4 gload_lds must retire; t+1's stay in flight
//   s_barrier + sched_barrier(0)  <- all waves' tile-t loads now LDS-visible (each waited its own)
//   issue tile t+2's 4 gload_lds into buf[(t+2)%3]  <- freed: last read at t-1, before barrier t
//   ds_read frags(buf t) ; 16 MFMA
// vmcnt never reaches 0 until the last step -> loads flow continuously, 2 iterations of cover.
// Hang-audit (round 3): uniform control flow (no divergent barriers), FIFO vmcnt retirement
// (8 outstanding -> wait 4 -> stage 4), WAR on buf[(t+2)%3] ordered by barrier t. Safe.
// f32-A fallback: uniform branch, reg-stage + pk2 + ds_write, conservative vmcnt(0)/lgkmcnt(0).
// Grid: (M/128)*(N/128), bijective XCD-chunked swizzle, nb-inner (A-panel pairs share an XCD L2).
// fuse_eler: each wave's 64 cols = exactly 2 heads -> el/er in-epilogue.
__global__ __launch_bounds__(256) void k_gemm128(const void* __restrict__ A,
                                                 const __hip_bfloat16* __restrict__ Bt,
                                                 __hip_bfloat16* __restrict__ C,
                                                 int M, int K, int N,
                                                 const int* __restrict__ flag, int force_bf,
                                                 const float* __restrict__ al,
                                                 const float* __restrict__ ar,
                                                 float* __restrict__ el,
                                                 float* __restrict__ er, int fuse_eler) {
  __shared__ unsigned short sA[3][128 * 32];   // 3 x 8 KB, linear [row][32]
  __shared__ unsigned short sB[3][128 * 32];
  const int isbf = force_bf ? 1 : *flag;
  // bijective XCD-chunked swizzle (m204): logical id = mb*nblk + nb
  int nwg = gridDim.x;
  int q = nwg >> 3, r = nwg & 7;
  int xcd = blockIdx.x & 7, lid = blockIdx.x >> 3;
  int logical = (xcd < r ? xcd * (q + 1) : r * (q + 1) + (xcd - r) * q) + lid;
  int nblk = N >> 7;
  int mb = logical / nblk;
  int nb = logical - mb * nblk;
  int m0 = mb * 128, n0 = nb * 128;
  int tid = threadIdx.x;
  int wave = tid >> 6, lane = tid & 63;
  int wm = (wave >> 1) * 64, wn = (wave & 1) * 64;
  int lm = lane & 15, quad = lane >> 4;
  // staging chunk ids: each wave covers 128 contiguous 16B chunks (2 issues x 64 lanes)
  int c0 = (wave << 7) + lane, c1 = c0 + 64;
  int rA0 = c0 >> 2, rA1 = c1 >> 2;             // tile row of each chunk
  int col0 = (c0 & 3) << 3, col1 = (c1 & 3) << 3;  // element offset within row
  int gr0 = m0 + rA0; if (gr0 > M - 1) gr0 = M - 1;  // clamp tail rows (no OOB)
  int gr1 = m0 + rA1; if (gr1 > M - 1) gr1 = M - 1;
  const unsigned short* Ab = (const unsigned short*)A;
  const float* Af = (const float*)A;
  const unsigned short* Bb = (const unsigned short*)Bt;
  size_t aog0 = (size_t)gr0 * K + col0;
  size_t aog1 = (size_t)gr1 * K + col1;
  size_t bog0 = (size_t)(n0 + rA0) * K + col0;
  size_t bog1 = (size_t)(n0 + rA1) * K + col1;
  int lo0 = c0 << 3, lo1 = c1 << 3;             // LDS element offsets of the two chunks
  // fragment LDS byte offsets within a buffer (row pitch 64B)
  int fq = quad << 4;
  int aoff[4], boff[4];
  #pragma unroll
  for (int i = 0; i < 4; i++) {
    aoff[i] = ((wm + i * 16 + lm) << 6) + fq;
    boff[i] = ((wn + i * 16 + lm) << 6) + fq;
  }
  f32x4 acc[4][4] = {};
  int nk = K >> 5;

  // stage tile j into buffer b (bf16: 4 gload_lds, vmcnt+4; f32: reg+pack+ds_write, drained)
  #define STAGE_TILE(j, b)                                                              \
    do {                                                                                \
      size_t ko = (size_t)(j) << 5;                                                     \
      if (isbf) {                                                                       \
        gload16(Ab + aog0 + ko, &sA[(b)][lo0]);                                         \
        gload16(Ab + aog1 + ko, &sA[(b)][lo1]);                                         \
        gload16(Bb + bog0 + ko, &sB[(b)][lo0]);                                         \
        gload16(Bb + bog1 + ko, &sB[(b)][lo1]);                                         \
      } else {                                                                          \
        gload16(Bb + bog0 + ko, &sB[(b)][lo0]);                                         \
        gload16(Bb + bog1 + ko, &sB[(b)][lo1]);                                         \
        const float* p0 = Af + aog0 + ko;                                               \
        const float* p1 = Af + aog1 + ko;                                               \
        float4 x0 = *(const float4*)p0, y0 = *(const float4*)(p0 + 4);                  \
        float4 x1 = *(const float4*)p1, y1 = *(const float4*)(p1 + 4);                  \
        *(uint4*)&sA[(b)][lo0] =                                                        \
            make_uint4(pk2(x0.x, x0.y), pk2(x0.z, x0.w), pk2(y0.x, y0.y), pk2(y0.z, y0.w)); \
        *(uint4*)&sA[(b)][lo1] =                                                        \
            make_uint4(pk2(x1.x, x1.y), pk2(x1.z, x1.w), pk2(y1.x, y1.y), pk2(y1.z, y1.w)); \
        asm volatile("s_waitcnt lgkmcnt(0)" ::: "memory");                              \
      }                                                                                 \
    } while (0)

  // ---- prologue: stage tiles 0 and 1 ----
  STAGE_TILE(0, 0);
  if (nk > 1) STAGE_TILE(1, 1);
  int bufT = 0;            // buffer holding tile t
  int bufP = 2;            // buffer receiving tile t+2
  for (int t = 0; t < nk; ++t) {
    // wait own tile-t loads (leave t+1's in flight), then workgroup barrier
    if (isbf) {
      if (t + 1 < nk) asm volatile("s_waitcnt vmcnt(4)" ::: "memory");
      else            asm volatile("s_waitcnt vmcnt(0)" ::: "memory");
    } else {
      asm volatile("s_waitcnt vmcnt(0)" ::: "memory");
    }
    __builtin_amdgcn_s_barrier();
    __builtin_amdgcn_sched_barrier(0);
    // issue tile t+2 into the buffer last read at tile t-1 (safe: reads done pre-barrier)
    if (t + 2 < nk) STAGE_TILE(t + 2, bufP);
    __builtin_amdgcn_sched_barrier(0);
    const char* sAb = (const char*)&sA[bufT][0];
    const char* sBb = (const char*)&sB[bufT][0];
    bf16x8 af[4], bfr[4];
    #pragma unroll
    for (int i = 0; i < 4; i++) {
      af[i]  = *(const bf16x8*)(sAb + aoff[i]);
      bfr[i] = *(const bf16x8*)(sBb + boff[i]);
    }
    #pragma unroll
    for (int mi = 0; mi < 4; mi++)
      #pragma unroll
      for (int ni = 0; ni < 4; ni++)
        acc[mi][ni] = __builtin_amdgcn_mfma_f32_16x16x32_bf16(af[mi], bfr[ni], acc[mi][ni], 0, 0, 0);
    __builtin_amdgcn_sched_barrier(0);
    bufT = (bufT == 2) ? 0 : bufT + 1;
    bufP = (bufP == 2) ? 0 : bufP + 1;
  }
  #undef STAGE_TILE
  // C/D layout: col = lane&15, row = quad*4 + r (m89/m91 verified)
  #pragma unroll
  for (int mi = 0; mi < 4; mi++) {
    #pragma unroll
    for (int r2 = 0; r2 < 4; r2++) {
      int gm = m0 + wm + mi * 16 + (quad << 2) + r2;
      if (gm < M) {
        #pragma unroll
        for (int ni = 0; ni < 4; ni++) {
          int gn = n0 + wn + ni * 16 + lm;
          C[(size_t)gm * N + gn] = __float2bfloat16(acc[mi][ni][r2]);
        }
      }
    }
  }
  if (fuse_eler) {
    // this wave's cols n0+wn .. n0+wn+63 = heads h0, h0+1
    int h0 = (n0 + wn) >> 5;
    float ala[4], ara[4];
    #pragma unroll
    for (int ni = 0; ni < 4; ni++) {
      int idx = (h0 + (ni >> 1)) * DHEAD + ((ni & 1) << 4) + lm;
      ala[ni] = al[idx];
      ara[ni] = ar[idx];
    }
    #pragma unroll
    for (int mi = 0; mi < 4; mi++)
      #pragma unroll
      for (int r2 = 0; r2 < 4; r2++) {
        int gm = m0 + wm + mi * 16 + (quad << 2) + r2;
        #pragma unroll
        for (int hp = 0; hp < 2; hp++) {
          float pl = acc[mi][2 * hp][r2] * ala[2 * hp] + acc[mi][2 * hp + 1][r2] * ala[2 * hp + 1];
          float pr = acc[mi][2 * hp][r2] * ara[2 * hp] + acc[mi][2 * hp + 1][r2] * ara[2 * hp + 1];
          #pragma unroll
          for (int d = 1; d < 16; d <<= 1) {   // butterfly over the 16 lm lanes (same quad)
            pl += __shfl_xor(pl, d, 16);
            pr += __shfl_xor(pr, d, 16);
          }
          if (lm == 0 && gm < M) {
            el[gm * HEADS + h0 + hp] = pl;
            er[gm * HEADS + h0 + hp] = pr;
          }
        }
      }
  }
}

// ---------------- MFMA bf16 GEMM, 64x64 tile (kept for layer 2, N=64) ----------------
__global__ __launch_bounds__(256) void k_gemm64(const void* __restrict__ A,
                                                const __hip_bfloat16* __restrict__ Bt,
                                                __hip_bfloat16* __restrict__ C,
                                                int M, int K, int N,
                                                const int* __restrict__ flag, int force_bf,
                                                const float* __restrict__ al,
                                                const float* __restrict__ ar,
                                                float* __restrict__ el,
                                                float* __restrict__ er, int fuse_eler) {
  __shared__ unsigned short As[64][40];  // 80 B pitch: 16B-aligned rows, spreads banks
  __shared__ unsigned short Bs[64][40];
  const int isbf = force_bf ? 1 : *flag;
  int nblk = N >> 6;
  int per = nblk << 3;                 // blocks per group
  int g = blockIdx.x / per;
  int i2 = blockIdx.x - g * per;
  int mb = g * 8 + (i2 & 7);
  int nb = i2 >> 3;
  int m0 = mb * 64, n0 = nb * 64;
  if (m0 >= M) return;
  int tid = threadIdx.x;
  int lrow = tid >> 2;          // 0..63
  int lcol = (tid & 3) * 8;     // 0,8,16,24
  int wave = tid >> 6, lane = tid & 63;
  int wm = (wave >> 1) * 32, wn = (wave & 1) * 32;
  int lm = lane & 15, quad = lane >> 4;
  f32x4 acc[2][2] = {};
  // prologue load for k0 = 0
  uint4 av = loadA(A, isbf, m0 + lrow, M, K, lcol);
  uint4 bv = *(const uint4*)(Bt + (size_t)(n0 + lrow) * K + lcol);
  for (int k0 = 0; k0 < K; k0 += 32) {
    __syncthreads();            // previous iteration's LDS reads done
    *(uint4*)(&As[lrow][lcol]) = av;
    *(uint4*)(&Bs[lrow][lcol]) = bv;
    __syncthreads();
    // issue k+1's loads now; they drain behind the MFMA section below
    uint4 avn = make_uint4(0u, 0u, 0u, 0u), bvn = make_uint4(0u, 0u, 0u, 0u);
    if (k0 + 32 < K) {
      avn = loadA(A, isbf, m0 + lrow, M, K, k0 + 32 + lcol);
      bvn = *(const uint4*)(Bt + (size_t)(n0 + lrow) * K + k0 + 32 + lcol);
    }
    bf16x8 af[2], bfr[2];
    #pragma unroll
    for (int i = 0; i < 2; i++) {
      af[i]  = *(const bf16x8*)(&As[wm + i * 16 + lm][quad * 8]);
      bfr[i] = *(const bf16x8*)(&Bs[wn + i * 16 + lm][quad * 8]);
    }
    #pragma unroll
    for (int mi = 0; mi < 2; mi++)
      #pragma unroll
      for (int ni = 0; ni < 2; ni++)
        acc[mi][ni] = __builtin_amdgcn_mfma_f32_16x16x32_bf16(af[mi], bfr[ni], acc[mi][ni], 0, 0, 0);
    av = avn; bv = bvn;
  }
  // C/D layout: col = lane&15, row = quad*4 + r  (m89/m91 verified)
  #pragma unroll
  for (int mi = 0; mi < 2; mi++)
    #pragma unroll
    for (int ni = 0; ni < 2; ni++)
      #pragma unroll
      for (int r = 0; r < 4; r++) {
        int gm = m0 + wm + mi * 16 + quad * 4 + r;
        int gn = n0 + wn + ni * 16 + lm;
        if (gm < M) C[(size_t)gm * N + gn] = __float2bfloat16(acc[mi][ni][r]);
      }
  if (fuse_eler) {
    int hg = (n0 + wn) >> 5;
    float ala[2], ara[2];
    #pragma unroll
    for (int ni = 0; ni < 2; ni++) {
      ala[ni] = al[hg * DHEAD + ni * 16 + lm];
      ara[ni] = ar[hg * DHEAD + ni * 16 + lm];
    }
    #pragma unroll
    for (int mi = 0; mi < 2; mi++)
      #pragma unroll
      for (int r = 0; r < 4; r++) {
        float pl = acc[mi][0][r] * ala[0] + acc[mi][1][r] * ala[1];
        float pr = acc[mi][0][r] * ara[0] + acc[mi][1][r] * ara[1];
        #pragma unroll
        for (int d = 1; d < 16; d <<= 1) {
          pl += __shfl_xor(pl, d, 16);
          pr += __shfl_xor(pr, d, 16);
        }
        int gm = m0 + wm + mi * 16 + quad * 4 + r;
        if (lm == 0 && gm < M) {
          el[gm * HEADS + hg] = pl;
          er[gm * HEADS + hg] = pr;
        }
      }
  }
}

// ---------------- el/er for layer 2 (1 head, 40 dims, stride 64) ----------------
__global__ void k_eler2(const __hip_bfloat16* __restrict__ feat2,
                        const float* __restrict__ al, const float* __restrict__ ar,
                        float* __restrict__ el, float* __restrict__ er) {
  int n = blockIdx.x * blockDim.x + threadIdx.x;
  if (n >= N_NODES) return;
  const __hip_bfloat16* f = feat2 + (size_t)n * NCLS_PAD;
  float sl = 0.f, sr = 0.f;
  for (int d = 0; d < N_CLS; d++) {
    float v = __bfloat162float(f[d]);
    sl += v * al[d];
    sr += v * ar[d];
  }
  el[n] = sl;
  er[n] = sr;
}

// ---------------- fused edge-softmax + aggregation, 8 slots x 32 lanes ----------------
// lane owns 8 channels (uint4/edge). No max-subtraction (shift-invariant, exp clamped).
// Unroll-2: two independent csr->el/feat gather chains in flight.
// f32x2 accumulators -> v_pk_fma_f32; 32-bit byte offsets -> saddr+voffset loads.
__global__ __launch_bounds__(256) void k_aggregate8(const int* __restrict__ rowptr,
                                                    const int* __restrict__ csr_src,
                                                    const uint4* __restrict__ feat_rows,
                                                    const float* __restrict__ el,
                                                    const float* __restrict__ er,
                                                    const float* __restrict__ bias,
                                                    __hip_bfloat16* __restrict__ out) {
  __shared__ float lds_acc[8][256];
  __shared__ float lds_l[8][32];
  int n = blockIdx.x;
  int t = threadIdx.x;
  int slot = t >> 5;      // 0..7
  int c = t & 31;         // channel group: channels c*8..c*8+7
  int hh = c >> 2;        // head of this group
  float er_n = er[n * HEADS + hh];
  int beg = rowptr[n], end = rowptr[n + 1];
  float l = 0.f;
  f32x2 a0 = {0.f, 0.f}, a1 = {0.f, 0.f}, a2 = {0.f, 0.f}, a3 = {0.f, 0.f};
  const char* fb = (const char*)feat_rows;
  unsigned cb = (unsigned)c << 4;
  int i = beg + slot;
  for (; i + 8 < end; i += 16) {
    int s1 = csr_src[i];
    int s2 = csr_src[i + 8];
    float el1 = el[s1 * HEADS + hh];
    float el2 = el[s2 * HEADS + hh];
    uint4 f1 = *(const uint4*)(fb + (((unsigned)s1 << 9) | cb));
    uint4 f2 = *(const uint4*)(fb + (((unsigned)s2 << 9) | cb));
    float x1 = el1 + er_n, x2 = el2 + er_n;
    float e1 = x1 > 0.f ? x1 : 0.2f * x1;
    float e2 = x2 > 0.f ? x2 : 0.2f * x2;
    float p1 = __expf(fminf(e1, 60.f));
    float p2 = __expf(fminf(e2, 60.f));
    l += p1 + p2;
    a0 += bpair(f1.x) * p1; a1 += bpair(f1.y) * p1;
    a2 += bpair(f1.z) * p1; a3 += bpair(f1.w) * p1;
    a0 += bpair(f2.x) * p2; a1 += bpair(f2.y) * p2;
    a2 += bpair(f2.z) * p2; a3 += bpair(f2.w) * p2;
  }
  if (i < end) {
    int s = csr_src[i];
    float elv = el[s * HEADS + hh];
    uint4 fv = *(const uint4*)(fb + (((unsigned)s << 9) | cb));
    float x = elv + er_n;
    float e = x > 0.f ? x : 0.2f * x;
    float p = __expf(fminf(e, 60.f));
    l += p;
    a0 += bpair(fv.x) * p; a1 += bpair(fv.y) * p;
    a2 += bpair(fv.z) * p; a3 += bpair(fv.w) * p;
  }
  *(float4*)&lds_acc[slot][c * 8]     = make_float4(a0.x, a0.y, a1.x, a1.y);
  *(float4*)&lds_acc[slot][c * 8 + 4] = make_float4(a2.x, a2.y, a3.x, a3.y);
  lds_l[slot][c] = l;
  __syncthreads();
  float a = 0.f, L = 0.f;
  #pragma unroll
  for (int s2 = 0; s2 < 8; s2++) { a += lds_acc[s2][t]; L += lds_l[s2][t >> 3]; }
  float o = a / fmaxf(L, 1e-9f) + bias[t];
  o = fmaxf(o, 0.f);                            // ReLU (layers 0,1)
  out[(size_t)n * HID + t] = __float2bfloat16(o);
}

// ---------------- layer 2 aggregate: 32 slots x 8 lanes (64-ch padded rows) ----------------
__global__ __launch_bounds__(256) void k_aggregate1(const int* __restrict__ rowptr,
                                                    const int* __restrict__ csr_src,
                                                    const uint4* __restrict__ fr2,  // [N][8] uint4
                                                    const float* __restrict__ el,
                                                    const float* __restrict__ er,
                                                    const float* __restrict__ bias,
                                                    void* __restrict__ out,
                                                    const int* __restrict__ flag) {
  __shared__ float lds_acc[32][64];
  __shared__ float lds_l[32][8];
  int isbf = *flag;
  int n = blockIdx.x;
  int t = threadIdx.x;
  int slot = t >> 3;      // 0..31
  int c = t & 7;
  float er_n = er[n];
  int beg = rowptr[n], end = rowptr[n + 1];
  float l = 0.f;
  f32x2 a0 = {0.f, 0.f}, a1 = {0.f, 0.f}, a2 = {0.f, 0.f}, a3 = {0.f, 0.f};
  const char* fb = (const char*)fr2;
  unsigned cb = (unsigned)c << 4;
  int i = beg + slot;
  for (; i + 32 < end; i += 64) {
    int s1 = csr_src[i], s2 = csr_src[i + 32];
    float el1 = el[s1], el2 = el[s2];
    uint4 f1 = *(const uint4*)(fb + (((unsigned)s1 << 7) | cb));
    uint4 f2 = *(const uint4*)(fb + (((unsigned)s2 << 7) | cb));
    float x1 = el1 + er_n, x2 = el2 + er_n;
    float e1 = x1 > 0.f ? x1 : 0.2f * x1;
    float e2 = x2 > 0.f ? x2 : 0.2f * x2;
    float p1 = __expf(fminf(e1, 60.f));
    float p2 = __expf(fminf(e2, 60.f));
    l += p1 + p2;
    a0 += bpair(f1.x) * p1; a1 += bpair(f1.y) * p1;
    a2 += bpair(f1.z) * p1; a3 += bpair(f1.w) * p1;
    a0 += bpair(f2.x) * p2; a1 += bpair(f2.y) * p2;
    a2 += bpair(f2.z) * p2; a3 += bpair(f2.w) * p2;
  }
  if (i < end) {
    int s = csr_src[i];
    float x = el[s] + er_n;
    uint4 fv = *(const uint4*)(fb + (((unsigned)s << 7) | cb));
    float e = x > 0.f ? x : 0.2f * x;
    float p = __expf(fminf(e, 60.f));
    l += p;
    a0 += bpair(fv.x) * p; a1 += bpair(fv.y) * p;
    a2 += bpair(fv.z) * p; a3 += bpair(fv.w) * p;
  }
  *(float4*)&lds_acc[slot][c * 8]     = make_float4(a0.x, a0.y, a1.x, a1.y);
  *(float4*)&lds_acc[slot][c * 8 + 4] = make_float4(a2.x, a2.y, a3.x, a3.y);
  lds_l[slot][c] = l;
  __syncthreads();
  if (t < N_CLS) {
    float a = 0.f, L = 0.f;
    #pragma unroll
    for (int s2 = 0; s2 < 32; s2++) { a += lds_acc[s2][t]; L += lds_l[s2][t >> 3]; }
    float o = a / fmaxf(L, 1e-9f) + bias[t];    // no ReLU on output layer
    if (isbf) ((__hip_bfloat16*)out)[(size_t)n * N_CLS + t] = __float2bfloat16(o);
    else      ((float*)out)[(size_t)n * N_CLS + t] = o;
  }
}

// ---------------- launch ----------------
static inline size_t align_up(size_t x) { return (x + 255) & ~(size_t)255; }

extern "C" void kernel_launch(void* const* d_in, const int* in_sizes, int n_in,
                              void* d_out, int out_size, void* d_ws, size_t ws_size,
                              hipStream_t stream) {
  const void* in_feat = d_in[0];
  const int* src = (const int*)d_in[1];
  const int* dst = (const int*)d_in[2];
  const void* W0  = d_in[3];
  const void* al0 = d_in[4];
  const void* ar0 = d_in[5];
  const void* b0  = d_in[6];
  const void* W1  = d_in[7];
  const void* al1 = d_in[8];
  const void* ar1 = d_in[9];
  const void* b1  = d_in[10];
  const void* W2  = d_in[11];
  const void* al2 = d_in[12];
  const void* ar2 = d_in[13];
  const void* b2  = d_in[14];

  char* p = (char*)d_ws;
  int* flag = (int*)p;                   p += 256;
  float* att = (float*)p;                p += align_up(AT_SZ * sizeof(float));
  int* rowptr = (int*)p;                 p += align_up((N_NODES + 1) * sizeof(int));
  int* cursor = (int*)p;                 p += align_up(N_NODES * sizeof(int));
  int* csr_src = (int*)p;                p += align_up(N_EDGES * sizeof(int));
  int* partial = (int*)p;                p += align_up(SCAN_NB * sizeof(int));
  __hip_bfloat16* feat16 = (__hip_bfloat16*)p; p += align_up((size_t)N_NODES * HID * sizeof(__hip_bfloat16));
  __hip_bfloat16* h16 = (__hip_bfloat16*)p;    p += align_up((size_t)N_NODES * HID * sizeof(__hip_bfloat16));
  float* el = (float*)p;                 p += align_up((size_t)N_NODES * HEADS * sizeof(float));
  float* er = (float*)p;                 p += align_up((size_t)N_NODES * HEADS * sizeof(float));
  __hip_bfloat16* w0t = (__hip_bfloat16*)p;    p += align_up((size_t)HID * IN_F * sizeof(__hip_bfloat16));
  __hip_bfloat16* w1t = (__hip_bfloat16*)p;    p += align_up((size_t)HID * HID * sizeof(__hip_bfloat16));
  __hip_bfloat16* w2t = (__hip_bfloat16*)p;    p += align_up((size_t)NCLS_PAD * HID * sizeof(__hip_bfloat16));

  const int EB = (N_EDGES + 255) / 256;
  const int MB64 = (N_NODES + 63) / 64;          // 782
  const int GROUPS = (MB64 + 7) / 8;             // 98
  const int G1 = GROUPS * 8 * 1;                 // layer-2 swizzled grid (784)
  const int MB128 = (N_NODES + 127) / 128;       // 391
  const int GX = MB128 * 2;                      // 128x128 tiles, N=256 (782)

  // ---- dtype detection + constant prep + cursor zero ----
  k_detect_prep<<<1, 256, 0, stream>>>((const unsigned short*)in_feat, flag,
                                       al0, ar0, al1, ar1, al2, ar2, b0, b1, b2, att, cursor);

  // ---- CSR build ----
  k_hist<<<EB, 256, 0, stream>>>(dst, cursor);
  k_scan_blocks<<<SCAN_NB, SCAN_B, 0, stream>>>(cursor, rowptr, partial);
  k_scan_partials<<<1, 128, 0, stream>>>(partial, rowptr);
  k_scan_add<<<(N_NODES + 255) / 256, 256, 0, stream>>>(rowptr, partial, cursor);
  k_scatter<<<EB, 256, 0, stream>>>(src, dst, rowptr, cursor, csr_src);

  // ---- weight transposes (merged, -> bf16 [N][K]) ----
  k_transpose_all<<<(TW2 + 255) / 256, 256, 0, stream>>>(W0, W1, W2, w0t, w1t, w2t, flag);

  // ---- layer 0 (cast + el/er fused into GEMM) ----
  k_gemm128<<<GX, 256, 0, stream>>>(in_feat, w0t, feat16, N_NODES, IN_F, HID, flag, 0,
                                    att + AT_AL0, att + AT_AR0, el, er, 1);
  k_aggregate8<<<N_NODES, 256, 0, stream>>>(rowptr, csr_src, (const uint4*)feat16, el, er, att + AT_B0, h16);

  // ---- layer 1 ----
  k_gemm128<<<GX, 256, 0, stream>>>(h16, w1t, feat16, N_NODES, HID, HID, flag, 1,
                                    att + AT_AL1, att + AT_AR1, el, er, 1);
  k_aggregate8<<<N_NODES, 256, 0, stream>>>(rowptr, csr_src, (const uint4*)feat16, el, er, att + AT_B1, h16);

  // ---- layer 2 (feat16 reused as [N][64] padded feat2) ----
  k_gemm64<<<G1, 256, 0, stream>>>(h16, w2t, feat16, N_NODES, HID, NCLS_PAD, flag, 1,
                                   nullptr, nullptr, nullptr, nullptr, 0);
  k_eler2<<<(N_NODES + 255) / 256, 256, 0, stream>>>(feat16, att + AT_AL2, att + AT_AR2, el, er);
  k_aggregate1<<<N_NODES, 256, 0, stream>>>(rowptr, csr_src, (const uint4*)feat16, el, er, att + AT_B2, d_out, flag);
}